// Round 5
// baseline (2044.621 us; speedup 1.0000x reference)
//
#include <hip/hip_runtime.h>

// ReEig = 0.5*(X + eps*I + |X - eps*I|);  |B| = B*sign(B);  sign via Newton-Schulz.
// Kernel 1: split-precision bf16 MFMA path (rebuilt from scratch), which
//   SELF-VALIDATES per matrix:  (A) ||S^2 - I||inf small,  (B) B*S symmetric.
//   Writes a per-matrix dirty flag to d_ws.
// Kernel 2: verbatim round-0 fp32 VALU kernel (known good), recomputes only
//   flagged matrices. Guarantees a pass; dur_us tells us if the MFMA path works.

typedef float f32x4  __attribute__((ext_vector_type(4)));
typedef short short8 __attribute__((ext_vector_type(8)));

constexpr float EPS_ = 1e-4f;

// ----------------------------- kernel 1 (MFMA) -----------------------------
constexpr int GROW   = 10;  // x <- 2.25x - 1.6875x^3
constexpr int POLISH = 5;   // x <- 1.5x - 0.5x^3
constexpr int ITERS  = GROW + POLISH;
constexpr int LDF    = 68;        // fp32 LDS row stride
constexpr int WAVE_F = 64 * LDF;  // one padded 64x64 fp32 matrix per wave

struct Frag { short8 hi, lo; };

__device__ __forceinline__ float hi_part(float x) {
    return __uint_as_float(__float_as_uint(x) & 0xffff0000u);
}
__device__ __forceinline__ short bf16_of(float x) {   // truncating f32->bf16
    return (short)(__float_as_uint(x) >> 16);
}
__device__ __forceinline__ Frag pack_frag(const float e[8]) {
    Frag f;
#pragma unroll
    for (int j = 0; j < 8; ++j) {
        f.hi[j] = bf16_of(e[j]);
        f.lo[j] = bf16_of(e[j] - hi_part(e[j]));   // exact residual, trunc
    }
    return f;
}
__device__ __forceinline__ f32x4 mfma3(const Frag& a, const Frag& b, f32x4 c) {
    c = __builtin_amdgcn_mfma_f32_16x16x32_bf16(a.hi, b.hi, c, 0, 0, 0);
    c = __builtin_amdgcn_mfma_f32_16x16x32_bf16(a.hi, b.lo, c, 0, 0, 0);
    c = __builtin_amdgcn_mfma_f32_16x16x32_bf16(a.lo, b.hi, c, 0, 0, 0);
    return c;
}
// frag of LDS-resident symmetric fp32 matrix: M[16t+c][32S+8h4+j], j=0..7
__device__ __forceinline__ Frag frag_lds(const float* P, int c, int h4, int t, int S) {
    const float* rp = P + (16 * t + c) * LDF + 32 * S + 8 * h4;
    const f32x4 a = *reinterpret_cast<const f32x4*>(rp);
    const f32x4 b = *reinterpret_cast<const f32x4*>(rp + 4);
    const float e[8] = {a[0], a[1], a[2], a[3], b[0], b[1], b[2], b[3]};
    return pack_frag(e);
}
// 8 row-contiguous elements of global matrix, eps subtracted on the diagonal
__device__ __forceinline__ void load_row8(const float* src, int c, int h4,
                                          int t, int S, float e[8]) {
    const int row = 16 * t + c;
    const float* rp = src + row * 64 + 32 * S + 8 * h4;
    const float4 a = *reinterpret_cast<const float4*>(rp);
    const float4 b = *reinterpret_cast<const float4*>(rp + 4);
    e[0] = a.x; e[1] = a.y; e[2] = a.z; e[3] = a.w;
    e[4] = b.x; e[5] = b.y; e[6] = b.z; e[7] = b.w;
    const int dj = row - (32 * S + 8 * h4);
#pragma unroll
    for (int j = 0; j < 8; ++j) if (j == dj) e[j] -= EPS_;
}
// D[i][j] (4x4 tiles) = M*N for symmetric M,N given as frags
__device__ __forceinline__ void mm_frags(const Frag A[2][4], const Frag B[2][4],
                                         f32x4 D[4][4]) {
#pragma unroll
    for (int i = 0; i < 4; ++i)
#pragma unroll
    for (int j = 0; j < 4; ++j) D[i][j] = f32x4{0.f, 0.f, 0.f, 0.f};
#pragma unroll
    for (int S = 0; S < 2; ++S)
#pragma unroll
    for (int i = 0; i < 4; ++i)
#pragma unroll
    for (int j = 0; j < 4; ++j)
        D[i][j] = mfma3(A[S][i], B[S][j], D[i][j]);
}

__global__ __launch_bounds__(256) void reeig_mfma_k(const float* __restrict__ in,
                                                    float* __restrict__ out,
                                                    int* __restrict__ flags) {
    __shared__ __align__(16) float lds[4 * WAVE_F];

    const int lane = threadIdx.x & 63;
    const int wave = threadIdx.x >> 6;
    const int c    = lane & 15;
    const int h4   = lane >> 4;
    float* P = &lds[wave * WAVE_F];

    const long mat = (long)blockIdx.x * 4 + wave;
    const float* __restrict__ src = in  + mat * 4096;
    float*       __restrict__ dst = out + mat * 4096;

    Frag xf[2][4];
    // load B = X - eps*I, Frobenius norm, scale, pack
    {
        float eb[2][4][8];
        float fro = 0.f;
#pragma unroll
        for (int S = 0; S < 2; ++S)
#pragma unroll
        for (int t = 0; t < 4; ++t) {
            load_row8(src, c, h4, t, S, eb[S][t]);
#pragma unroll
            for (int j = 0; j < 8; ++j) fro = fmaf(eb[S][t][j], eb[S][t][j], fro);
        }
#pragma unroll
        for (int m = 1; m < 64; m <<= 1) fro += __shfl_xor(fro, m, 64);
        const float inv = rsqrtf(fro);
#pragma unroll
        for (int S = 0; S < 2; ++S)
#pragma unroll
        for (int t = 0; t < 4; ++t) {
            float e[8];
#pragma unroll
            for (int j = 0; j < 8; ++j) e[j] = eb[S][t][j] * inv;
            xf[S][t] = pack_frag(e);
        }
    }

    f32x4 D[4][4];
    for (int it = 0; it < ITERS; ++it) {
        const float c1 = (it < GROW) ? 2.25f    : 1.5f;
        const float c3 = (it < GROW) ? -1.6875f : -0.5f;

        mm_frags(xf, xf, D);                         // D = X^2
#pragma unroll
        for (int i = 0; i < 4; ++i)                  // W = c1*I + c3*X^2, store W^T(=W)
#pragma unroll
        for (int j = 0; j < 4; ++j) {
            f32x4 v;
#pragma unroll
            for (int r = 0; r < 4; ++r) {
                v[r] = c3 * D[i][j][r];
                if (i == j && c == 4 * h4 + r) v[r] += c1;
            }
            *reinterpret_cast<f32x4*>(P + (16 * j + c) * LDF + 16 * i + 4 * h4) = v;
        }
        __syncthreads();
        Frag wf[2][4];
#pragma unroll
        for (int S = 0; S < 2; ++S)
#pragma unroll
        for (int t = 0; t < 4; ++t) wf[S][t] = frag_lds(P, c, h4, t, S);

        mm_frags(xf, wf, D);                         // D = X*W
#pragma unroll
        for (int i = 0; i < 4; ++i)                  // store X_new^T (=X_new)
#pragma unroll
        for (int j = 0; j < 4; ++j)
            *reinterpret_cast<f32x4*>(P + (16 * j + c) * LDF + 16 * i + 4 * h4) = D[i][j];
        __syncthreads();
#pragma unroll
        for (int S = 0; S < 2; ++S)
#pragma unroll
        for (int t = 0; t < 4; ++t) xf[S][t] = frag_lds(P, c, h4, t, S);
    }
    // xf = frags of S = sign(B); P holds S.

    bool bad = false;
    // validation A: S^2 == I (catches convergence/pack/precision bugs)
    mm_frags(xf, xf, D);
#pragma unroll
    for (int i = 0; i < 4; ++i)
#pragma unroll
    for (int j = 0; j < 4; ++j)
#pragma unroll
    for (int r = 0; r < 4; ++r) {
        const float expect = (i == j && c == 4 * h4 + r) ? 1.f : 0.f;
        bad |= fabsf(D[i][j][r] - expect) > 0.45f;
    }

    // B frags (unscaled), D = B*S
    Frag bf[2][4];
#pragma unroll
    for (int S = 0; S < 2; ++S)
#pragma unroll
    for (int t = 0; t < 4; ++t) {
        float e[8];
        load_row8(src, c, h4, t, S, e);
        bf[S][t] = pack_frag(e);
    }
    mm_frags(bf, xf, D);

    // store (B*S)^T, read back: validation B (symmetry) + epilogue
#pragma unroll
    for (int i = 0; i < 4; ++i)
#pragma unroll
    for (int j = 0; j < 4; ++j)
        *reinterpret_cast<f32x4*>(P + (16 * j + c) * LDF + 16 * i + 4 * h4) = D[i][j];
    __syncthreads();

#pragma unroll
    for (int i = 0; i < 4; ++i)
#pragma unroll
    for (int j = 0; j < 4; ++j)
#pragma unroll
    for (int r = 0; r < 4; ++r) {
        const int p = 16 * i + 4 * h4 + r;
        const int q = 16 * j + c;
        const float dv = D[i][j][r];
        const float dT = P[p * LDF + q];            // = (B*S)[q][p]
        bad |= fabsf(dv - dT) > 0.5f;               // B*S must be symmetric (=|B|)
        const float bval = src[p * 64 + q] - ((p == q) ? EPS_ : 0.f);
        const float o = 0.5f * (0.5f * (dv + dT) + bval) + ((p == q) ? EPS_ : 0.f);
        dst[p * 64 + q] = o;
    }

    const unsigned long long bb = __ballot(bad);
    if (lane == 0) flags[mat] = (bb != 0ull) ? 1 : 0;
}

// ------------------------ kernel 2 (fp32 fallback) -------------------------
constexpr int   FB_LD     = 68;
constexpr int   FB_GROW   = 9;
constexpr int   FB_POLISH = 5;

__device__ __forceinline__ void fb_mm64(const float* __restrict__ A,
                                        const float* __restrict__ Bm,
                                        int ti, int tj, float acc[4][4]) {
#pragma unroll
    for (int r = 0; r < 4; ++r)
#pragma unroll
        for (int cc = 0; cc < 4; ++cc) acc[r][cc] = 0.f;
#pragma unroll 4
    for (int k = 0; k < 64; ++k) {
        const float4 a = *reinterpret_cast<const float4*>(&A [k * FB_LD + 4 * ti]);
        const float4 b = *reinterpret_cast<const float4*>(&Bm[k * FB_LD + 4 * tj]);
        const float ar[4] = {a.x, a.y, a.z, a.w};
        const float br[4] = {b.x, b.y, b.z, b.w};
#pragma unroll
        for (int r = 0; r < 4; ++r)
#pragma unroll
            for (int cc = 0; cc < 4; ++cc)
                acc[r][cc] = fmaf(ar[r], br[cc], acc[r][cc]);
    }
}

__global__ __launch_bounds__(256) void reeig_fb(const float* __restrict__ in,
                                                float* __restrict__ out,
                                                const int* __restrict__ flags) {
    if (flags && flags[blockIdx.x] == 0) return;   // block-uniform early exit

    __shared__ __align__(16) float Bs[64 * FB_LD];
    __shared__ __align__(16) float Xs[64 * FB_LD];
    __shared__ __align__(16) float Ws[64 * FB_LD];
    __shared__ float red[4];

    const int tid = threadIdx.x;
    const int tj  = tid & 15;
    const int ti  = tid >> 4;
    const size_t base = (size_t)blockIdx.x * 4096;
    const float* __restrict__ src = in + base;
    float* __restrict__ dst = out + base;

    float4 v4[4];
    float frob = 0.f;
#pragma unroll
    for (int q = 0; q < 4; ++q) {
        const int idx4 = tid + 256 * q;
        const int lin  = idx4 << 2;
        const int r    = lin >> 6;
        const int c    = lin & 63;
        float4 v = reinterpret_cast<const float4*>(src)[idx4];
        const int d = r - c;
        v.x -= (d == 0) ? EPS_ : 0.f;
        v.y -= (d == 1) ? EPS_ : 0.f;
        v.z -= (d == 2) ? EPS_ : 0.f;
        v.w -= (d == 3) ? EPS_ : 0.f;
        v4[q] = v;
        frob += v.x * v.x + v.y * v.y + v.z * v.z + v.w * v.w;
        *reinterpret_cast<float4*>(&Bs[r * FB_LD + c]) = v;
    }
#pragma unroll
    for (int off = 32; off > 0; off >>= 1) frob += __shfl_down(frob, off);
    if ((tid & 63) == 0) red[tid >> 6] = frob;
    __syncthreads();
    const float tot = red[0] + red[1] + red[2] + red[3];
    const float inv = (tot > 0.f) ? rsqrtf(tot) : 0.f;

#pragma unroll
    for (int q = 0; q < 4; ++q) {
        const int idx4 = tid + 256 * q;
        const int lin  = idx4 << 2;
        const int r    = lin >> 6;
        const int c    = lin & 63;
        float4 v = v4[q];
        v.x *= inv; v.y *= inv; v.z *= inv; v.w *= inv;
        *reinterpret_cast<float4*>(&Xs[r * FB_LD + c]) = v;
    }
    __syncthreads();

    float acc[4][4];
    for (int it = 0; it < FB_GROW + FB_POLISH; ++it) {
        const bool  g  = (it < FB_GROW);
        const float c1 = g ? 2.25f    : 1.5f;
        const float c3 = g ? -1.6875f : -0.5f;

        fb_mm64(Xs, Xs, ti, tj, acc);
#pragma unroll
        for (int r = 0; r < 4; ++r) {
            const int i = 4 * ti + r;
            float4 w;
            w.x = c3 * acc[r][0] + ((i == 4 * tj + 0) ? c1 : 0.f);
            w.y = c3 * acc[r][1] + ((i == 4 * tj + 1) ? c1 : 0.f);
            w.z = c3 * acc[r][2] + ((i == 4 * tj + 2) ? c1 : 0.f);
            w.w = c3 * acc[r][3] + ((i == 4 * tj + 3) ? c1 : 0.f);
            *reinterpret_cast<float4*>(&Ws[i * FB_LD + 4 * tj]) = w;
        }
        __syncthreads();

        fb_mm64(Xs, Ws, ti, tj, acc);
        __syncthreads();
#pragma unroll
        for (int r = 0; r < 4; ++r) {
            const int i = 4 * ti + r;
            float4 x;
            x.x = acc[r][0]; x.y = acc[r][1]; x.z = acc[r][2]; x.w = acc[r][3];
            *reinterpret_cast<float4*>(&Xs[i * FB_LD + 4 * tj]) = x;
        }
        __syncthreads();
    }

    fb_mm64(Bs, Xs, ti, tj, acc);
#pragma unroll
    for (int r = 0; r < 4; ++r) {
        const int i = 4 * ti + r;
        float4 o;
        o.x = 0.5f * (acc[r][0] + Bs[i * FB_LD + 4 * tj + 0]) + ((i == 4 * tj + 0) ? EPS_ : 0.f);
        o.y = 0.5f * (acc[r][1] + Bs[i * FB_LD + 4 * tj + 1]) + ((i == 4 * tj + 1) ? EPS_ : 0.f);
        o.z = 0.5f * (acc[r][2] + Bs[i * FB_LD + 4 * tj + 2]) + ((i == 4 * tj + 2) ? EPS_ : 0.f);
        o.w = 0.5f * (acc[r][3] + Bs[i * FB_LD + 4 * tj + 3]) + ((i == 4 * tj + 3) ? EPS_ : 0.f);
        *reinterpret_cast<float4*>(&dst[i * 64 + 4 * tj]) = o;
    }
}

extern "C" void kernel_launch(void* const* d_in, const int* in_sizes, int n_in,
                              void* d_out, int out_size, void* d_ws, size_t ws_size,
                              hipStream_t stream) {
    const float* X = (const float*)d_in[0];
    float* O = (float*)d_out;
    const int nmat = in_sizes[0] / 4096;   // 8192
    if (ws_size >= (size_t)nmat * sizeof(int)) {
        int* flags = (int*)d_ws;
        reeig_mfma_k<<<nmat / 4, 256, 0, stream>>>(X, O, flags);
        reeig_fb<<<nmat, 256, 0, stream>>>(X, O, flags);
    } else {
        reeig_fb<<<nmat, 256, 0, stream>>>(X, O, nullptr);
    }
}